// Round 1
// baseline (717.739 us; speedup 1.0000x reference)
//
#include <hip/hip_runtime.h>
#include <math.h>

#define BB 256
#define DD 4096
#define MAXR 31
#define NCAND 32

// ---------------- threefry2x32 (JAX schedule) ----------------
__device__ __forceinline__ void tf2x32(unsigned k0, unsigned k1, unsigned c0, unsigned c1,
                                       unsigned &o0, unsigned &o1) {
  unsigned ks2 = k0 ^ k1 ^ 0x1BD11BDAu;
  unsigned x0 = c0 + k0;
  unsigned x1 = c1 + k1;
#define TF_ROT(v, r) (((v) << (r)) | ((v) >> (32 - (r))))
#define TF_R(r) { x0 += x1; x1 = TF_ROT(x1, r); x1 ^= x0; }
  TF_R(13) TF_R(15) TF_R(26) TF_R(6)   x0 += k1;  x1 += ks2 + 1u;
  TF_R(17) TF_R(29) TF_R(16) TF_R(24)  x0 += ks2; x1 += k0 + 2u;
  TF_R(13) TF_R(15) TF_R(26) TF_R(6)   x0 += k0;  x1 += k1 + 3u;
  TF_R(17) TF_R(29) TF_R(16) TF_R(24)  x0 += k1;  x1 += ks2 + 4u;
  TF_R(13) TF_R(15) TF_R(26) TF_R(6)   x0 += ks2; x1 += k0 + 5u;
#undef TF_R
#undef TF_ROT
  o0 = x0; o1 = x1;
}

// RNG MODE: jax_threefry_partitionable=True (default in JAX >= 0.4.36):
// random_bits(key,32)[n] = o0^o1 of tf(key,(0,n)); split(key,m)[i] = tf(key,(0,i)).
__device__ __forceinline__ unsigned tf_xor(unsigned k0, unsigned k1, unsigned c0, unsigned c1) {
  unsigned a, b; tf2x32(k0, k1, c0, c1, a, b); return a ^ b;
}

__device__ __forceinline__ float bits_to_unit(unsigned bits) {
  // (bits>>9) | 0x3f800000 bitcast - 1.0f  (exact; matches jax _uniform)
  return __uint_as_float(0x3f800000u | (bits >> 9)) - 1.0f;
}

// ---------------- fast accurate double log (~1e-13 rel) ----------------
__device__ __forceinline__ double dlog(double x) {
  unsigned long long ub = (unsigned long long)__double_as_longlong(x);
  int e = (int)((ub >> 52) & 0x7FFull) - 1022;
  double m = __longlong_as_double((long long)((ub & 0x000FFFFFFFFFFFFFull) | 0x3FE0000000000000ull));
  if (m < 0.70710678118654752440) { m *= 2.0; e -= 1; }
  double r = (m - 1.0) / (m + 1.0);       // |r| <= 0.1716
  double z = r * r;
  double s = fma(z, fma(z, fma(z, fma(z, fma(z, fma(z, 1.0/15.0, 1.0/13.0),
                1.0/11.0), 1.0/9.0), 1.0/7.0), 1.0/5.0), 1.0/3.0);
  double t2 = 2.0 * r;
  return fma((double)e, 0.69314718055994530942, fma(t2 * z, s, t2));
}

__device__ __forceinline__ double blockReduce256(double v, double* lds) {
  #pragma unroll
  for (int off = 32; off > 0; off >>= 1) v += __shfl_down(v, off);
  __syncthreads();
  if ((threadIdx.x & 63) == 0) lds[threadIdx.x >> 6] = v;
  __syncthreads();
  return lds[0] + lds[1] + lds[2] + lds[3];
}

// ---------------- K0: all small RNG draws ----------------
__global__ void k_rng(unsigned* __restrict__ keys_out, int* __restrict__ radius,
                      float* __restrict__ u_acc) {
  int t = threadIdx.x;  // 256 threads
  unsigned krad0, krad1, ksamp0, ksamp1, kacc0, kacc1;
  tf2x32(0u, 42u, 0u, 0u, krad0, krad1);   // split(key(42),3)[0]
  tf2x32(0u, 42u, 0u, 1u, ksamp0, ksamp1); // [1]
  tf2x32(0u, 42u, 0u, 2u, kacc0, kacc1);   // [2]
  if (t < MAXR) {                          // split(k_samp, 31)
    unsigned a, c;
    tf2x32(ksamp0, ksamp1, 0u, (unsigned)t, a, c);
    keys_out[2*t] = a; keys_out[2*t+1] = c;
  }
  // randint(k_rad,(B,1),1,32): k1,k2 = split(k_rad); span=31, multiplier=4
  unsigned k10, k11, k20, k21;
  tf2x32(krad0, krad1, 0u, 0u, k10, k11);
  tf2x32(krad0, krad1, 0u, 1u, k20, k21);
  unsigned hi = tf_xor(k10, k11, 0u, (unsigned)t);
  unsigned lo = tf_xor(k20, k21, 0u, (unsigned)t);
  unsigned off = ((hi % 31u) * 4u + (lo % 31u)) % 31u;
  radius[t] = 1 + (int)off;
  unsigned ab = tf_xor(kacc0, kacc1, 0u, (unsigned)t);  // uniform(k_acc,(B,))
  u_acc[t] = bits_to_unit(ab);
}

// ---------------- K1a: transpose x -> xT[D][B] ----------------
__global__ void k_transpose(const float* __restrict__ x, float* __restrict__ xT) {
  __shared__ float tile[32][33];
  int bx = blockIdx.x & 127;   // k-tile (D/32)
  int by = blockIdx.x >> 7;    // b-tile (B/32)
  int tx = threadIdx.x & 31, ty = threadIdx.x >> 5;  // 32 x 8
  #pragma unroll
  for (int r = 0; r < 32; r += 8)
    tile[ty + r][tx] = x[(size_t)(by*32 + ty + r)*DD + bx*32 + tx];
  __syncthreads();
  #pragma unroll
  for (int r = 0; r < 32; r += 8)
    xT[(size_t)(bx*32 + ty + r)*BB + by*32 + tx] = tile[tx][ty + r];
}

// ---------------- K1b: split-K fp32 GEMM  Cpart[kc] = xT^T(128xK) * W(Kx128) tile ----------------
__global__ __launch_bounds__(256) void k_gemm(const float* __restrict__ xT, const float* __restrict__ W,
                                              float* __restrict__ Cpart, int klen) {
  __shared__ float As[32][132];
  __shared__ float Bs[32][132];
  int nt = blockIdx.x, mt = blockIdx.y, kc = blockIdx.z;
  int t = threadIdx.x;
  int tx = t & 15, ty = t >> 4;
  int k0 = kc * klen;
  float acc[8][8] = {};
  for (int kb = 0; kb < klen; kb += 32) {
    #pragma unroll
    for (int p = 0; p < 4; p++) {
      int f = t + 256*p;
      int kk = f >> 5, mq = f & 31;
      *(float4*)&As[kk][mq*4] = *(const float4*)&xT[(size_t)(k0+kb+kk)*BB + mt*128 + mq*4];
      *(float4*)&Bs[kk][mq*4] = *(const float4*)&W [(size_t)(k0+kb+kk)*DD + nt*128 + mq*4];
    }
    __syncthreads();
    for (int kk = 0; kk < 32; kk++) {
      float a[8], bv[8];
      *(float4*)&a[0]  = *(const float4*)&As[kk][ty*8];
      *(float4*)&a[4]  = *(const float4*)&As[kk][ty*8+4];
      *(float4*)&bv[0] = *(const float4*)&Bs[kk][tx*8];
      *(float4*)&bv[4] = *(const float4*)&Bs[kk][tx*8+4];
      #pragma unroll
      for (int i = 0; i < 8; i++)
        #pragma unroll
        for (int j = 0; j < 8; j++)
          acc[i][j] = fmaf(a[i], bv[j], acc[i][j]);
    }
    __syncthreads();
  }
  float* Cp = Cpart + (size_t)kc * BB * DD;
  #pragma unroll
  for (int i = 0; i < 8; i++) {
    int m = mt*128 + ty*8 + i;
    float* row = &Cp[(size_t)m*DD + nt*128 + tx*8];
    *(float4*)&row[0] = *(float4*)&acc[i][0];
    *(float4*)&row[4] = *(float4*)&acc[i][4];
  }
}

// ---------------- K1c: reduce split-K, add bias, make sc_x ----------------
__global__ void k_reduce(const float* __restrict__ Cpart, const float* __restrict__ bias,
                         const float* __restrict__ x, float* __restrict__ grad,
                         float* __restrict__ sc, int KS) {
  int i = blockIdx.x * 256 + threadIdx.x;
  float acc = 0.0f;
  for (int kc = 0; kc < KS; kc++) acc += Cpart[(size_t)kc * BB * DD + i];
  float g = acc + bias[i & (DD-1)];
  grad[i] = g;
  float xv = x[i];
  sc[i] = (1.0f - 2.0f*xv) * g * 0.5f;   // score_change_x
}

// ---------------- K2: score_x[b] = 0.5*(x.grad + x.bias) ----------------
__global__ __launch_bounds__(256) void k_score(const float* __restrict__ x, const float* __restrict__ grad,
                                               const float* __restrict__ bias, double* __restrict__ score) {
  int b = blockIdx.x, t = threadIdx.x;
  double s1 = 0.0, s2 = 0.0;
  for (int k = 0; k < 16; k++) {
    int d = t + 256*k; size_t o = (size_t)b*DD + d;
    double xv = x[o];
    s1 += xv * (double)grad[o];
    s2 += xv * (double)bias[d];
  }
  __shared__ double lds[4];
  double S1 = blockReduce256(s1, lds);
  double S2 = blockReduce256(s2, lds);
  if (t == 0) score[b] = 0.5 * (S1 + S2);
}

// ---------------- K4: per (row,step) top-32 of sc_x + gumbel ----------------
__global__ __launch_bounds__(256) void k_cand(const float* __restrict__ sc_x,
                                              const unsigned* __restrict__ keys,
                                              int* __restrict__ cand_i) {
  int blk = blockIdx.x;
  int b = blk / MAXR, j = blk % MAXR;
  unsigned kk0 = keys[2*j], kk1 = keys[2*j+1];
  int t = threadIdx.x;
  float v[16];
  #pragma unroll
  for (int p = 0; p < 16; p++) {
    int d = t + 256*p;
    unsigned bits = tf_xor(kk0, kk1, 0u, (unsigned)(b*DD + d));
    float f = bits_to_unit(bits);
    float uu = (f == 0.0f) ? 1.17549435e-38f : f;       // uniform(minval=tiny)
    float t1 = (float)dlog((double)uu);                  // fp32-rounded inner log
    float g  = -(float)dlog((double)(-t1));              // gumbel, fp32-rounded
    v[p] = sc_x[(size_t)b*DD + d] + g;
  }
  unsigned alive = 0xFFFFu;
  __shared__ float ls_v[4];
  __shared__ int   ls_i[4];
  __shared__ int   win_i_s;
  for (int r = 0; r < NCAND; r++) {
    float bv = -INFINITY; int bi = 0x7FFFFFFF;
    #pragma unroll
    for (int p = 0; p < 16; p++) {
      int d = t + 256*p;
      if (((alive >> p) & 1u) && (v[p] > bv || (v[p] == bv && d < bi))) { bv = v[p]; bi = d; }
    }
    #pragma unroll
    for (int off = 32; off > 0; off >>= 1) {
      float ov = __shfl_down(bv, off);
      int   oi = __shfl_down(bi, off);
      if (ov > bv || (ov == bv && oi < bi)) { bv = ov; bi = oi; }
    }
    if ((t & 63) == 0) { ls_v[t >> 6] = bv; ls_i[t >> 6] = bi; }
    __syncthreads();
    if (t == 0) {
      float fv = ls_v[0]; int fi = ls_i[0];
      #pragma unroll
      for (int w = 1; w < 4; w++)
        if (ls_v[w] > fv || (ls_v[w] == fv && ls_i[w] < fi)) { fv = ls_v[w]; fi = ls_i[w]; }
      win_i_s = fi;
      cand_i[(size_t)blk * NCAND + r] = fi;
    }
    __syncthreads();
    int wi = win_i_s;
    if (t == (wi & 255)) alive &= ~(1u << (wi >> 8));
  }
}

// ---------------- K5: sequential per-row selection (blocked chain) ----------------
__global__ void k_select(const int* __restrict__ cand_i, int* __restrict__ idx_all) {
  __shared__ unsigned mask[64][128];   // 4096-bit taken mask per row
  int t = threadIdx.x;                 // 64 threads, 1 row each
  for (int w = 0; w < 128; w++) mask[t][w] = 0u;
  int b = blockIdx.x * 64 + t;
  for (int j = 0; j < MAXR; j++) {
    const int* ci = &cand_i[(size_t)(b*MAXR + j) * NCAND];
    int pick = ci[0];
    for (int r = 0; r < NCAND; r++) {
      int idx = ci[r];
      if (!((mask[t][idx >> 5] >> (idx & 31)) & 1u)) { pick = idx; break; }
    }
    idx_all[b*MAXR + j] = pick;
    mask[t][pick >> 5] |= (1u << (pick & 31));
  }
}

// ---------------- K6: y, grad_y (incremental), sc_y, score_y ----------------
__global__ __launch_bounds__(256) void k_y(const float* __restrict__ x, const float* __restrict__ W,
    const float* __restrict__ bias, const float* __restrict__ grad_x,
    const int* __restrict__ idx_all, const int* __restrict__ radius,
    float* __restrict__ yv, float* __restrict__ sc_y, double* __restrict__ score_y) {
  int b = blockIdx.x, t = threadIdx.x;
  __shared__ int   fidx[MAXR];
  __shared__ float fsgn[MAXR];
  int nf = radius[b];                      // active steps = j < radius
  if (t < nf) {
    int id = idx_all[b*MAXR + t];
    fidx[t] = id;
    fsgn[t] = 1.0f - 2.0f * x[(size_t)b*DD + id];  // +1 flip 0->1, -1 flip 1->0
  }
  __syncthreads();
  double s1 = 0.0, s2 = 0.0;
  for (int k = 0; k < 16; k++) {
    int d = t + 256*k;
    size_t o = (size_t)b*DD + d;
    float g = grad_x[o];
    float xval = x[o];
    float yval = xval;
    for (int jj = 0; jj < nf; jj++) {
      g = fmaf(fsgn[jj], W[(size_t)fidx[jj]*DD + d], g);  // W symmetric: row == col
      if (fidx[jj] == d) yval = 1.0f - xval;
    }
    yv[o] = yval;
    sc_y[o] = (1.0f - 2.0f*yval) * g * 0.5f;
    s1 += (double)yval * (double)g;
    s2 += (double)yval * (double)bias[d];
  }
  __shared__ double lds[4];
  double S1 = blockReduce256(s1, lds);
  double S2 = blockReduce256(s2, lds);
  if (t == 0) score_y[b] = 0.5 * (S1 + S2);
}

// ---------------- K7: masked log-softmax sums, accept, output ----------------
__global__ __launch_bounds__(256) void k_accept(const float* __restrict__ x, const float* __restrict__ yv,
    const float* __restrict__ sc_x, const float* __restrict__ sc_y,
    const int* __restrict__ idx_all, const int* __restrict__ radius,
    const double* __restrict__ score_x, const double* __restrict__ score_y,
    const float* __restrict__ u_acc, float* __restrict__ out) {
  int b = blockIdx.x, t = threadIdx.x;
  double sx = 0.0, sy = 0.0;
  for (int k = 0; k < 16; k++) {
    int d = t + 256*k; size_t o = (size_t)b*DD + d;
    sx += exp((double)sc_x[o]);
    sy += exp((double)sc_y[o]);
  }
  __shared__ double lds[4];
  double S = blockReduce256(sx, lds);   // full logsumexp denominator (fwd)
  double T = blockReduce256(sy, lds);   // (bwd)
  __shared__ float accf;
  if (t == 0) {
    int nf = radius[b];
    const int* ia = &idx_all[b*MAXR];
    double lf = 0.0, pre = 0.0;
    for (int jj = 0; jj < MAXR; jj++) {        // fwd: exclude idx sampled before j
      int id = ia[jj];
      double scv = (double)sc_x[(size_t)b*DD + id];
      if (jj < nf) lf += scv - dlog(S - pre);
      pre += exp(scv);
    }
    double lb = 0.0, suf = 0.0;
    for (int jj = MAXR-1; jj >= 0; jj--) {     // bwd: exclude idx sampled after j
      int id = ia[jj];
      double scv = (double)sc_y[(size_t)b*DD + id];
      if (jj < nf) lb += scv - dlog(T - suf);
      suf += exp(scv);
    }
    double log_acc = (lb + score_y[b]) - (lf + score_x[b]);
    accf = (exp(log_acc) >= (double)u_acc[b]) ? 1.0f : 0.0f;
  }
  __syncthreads();
  float a = accf;
  for (int k = 0; k < 16; k++) {
    int d = t + 256*k; size_t o = (size_t)b*DD + d;
    out[o] = a * yv[o] + (1.0f - a) * x[o];
  }
}

extern "C" void kernel_launch(void* const* d_in, const int* in_sizes, int n_in,
                              void* d_out, int out_size, void* d_ws, size_t ws_size,
                              hipStream_t stream) {
  const float* x    = (const float*)d_in[0];
  const float* W    = (const float*)d_in[1];
  const float* bias = (const float*)d_in[2];
  float* out = (float*)d_out;
  char* ws = (char*)d_ws;
  const size_t MB = 1ull << 20;

  float*    grad_x  = (float*)   (ws + 0*MB);
  float*    sc_x    = (float*)   (ws + 4*MB);
  float*    sc_y    = (float*)   (ws + 8*MB);
  float*    yv      = (float*)   (ws + 12*MB);
  float*    xT      = (float*)   (ws + 16*MB);
  int*      cand_i  = (int*)     (ws + 20*MB);
  int*      idx_all = (int*)     (ws + 21*MB);
  int*      radius  = (int*)     (ws + 21*MB + 64*1024);
  float*    u_acc   = (float*)   (ws + 21*MB + 68*1024);
  unsigned* keys    = (unsigned*)(ws + 21*MB + 72*1024);
  double*   score_x = (double*)  (ws + 21*MB + 80*1024);
  double*   score_y = (double*)  (ws + 21*MB + 96*1024);
  float*    Cpart   = (float*)   (ws + 22*MB);

  size_t base = 22*MB;
  int KS = 1;                                   // split-K factor (deterministic, no atomics)
  if      (ws_size >= base + 32*MB) KS = 8;
  else if (ws_size >= base + 16*MB) KS = 4;
  else if (ws_size >= base +  8*MB) KS = 2;

  k_rng      <<<1, 256, 0, stream>>>(keys, radius, u_acc);
  k_transpose<<<1024, 256, 0, stream>>>(x, xT);
  k_gemm     <<<dim3(DD/128, BB/128, KS), 256, 0, stream>>>(xT, W, Cpart, DD/KS);
  k_reduce   <<<BB*DD/256, 256, 0, stream>>>(Cpart, bias, x, grad_x, sc_x, KS);
  k_score    <<<BB, 256, 0, stream>>>(x, grad_x, bias, score_x);
  k_cand     <<<BB*MAXR, 256, 0, stream>>>(sc_x, keys, cand_i);
  k_select   <<<4, 64, 0, stream>>>(cand_i, idx_all);
  k_y        <<<BB, 256, 0, stream>>>(x, W, bias, grad_x, idx_all, radius, yv, sc_y, score_y);
  k_accept   <<<BB, 256, 0, stream>>>(x, yv, sc_x, sc_y, idx_all, radius, score_x, score_y, u_acc, out);
}

// Round 2
// 436.700 us; speedup vs baseline: 1.6435x; 1.6435x over previous
//
#include <hip/hip_runtime.h>
#include <math.h>

#define BB 256
#define DD 4096
#define MAXR 31
#define NCAND 4

// ---------------- threefry2x32 (JAX schedule) ----------------
__device__ __forceinline__ void tf2x32(unsigned k0, unsigned k1, unsigned c0, unsigned c1,
                                       unsigned &o0, unsigned &o1) {
  unsigned ks2 = k0 ^ k1 ^ 0x1BD11BDAu;
  unsigned x0 = c0 + k0;
  unsigned x1 = c1 + k1;
#define TF_ROT(v, r) (((v) << (r)) | ((v) >> (32 - (r))))
#define TF_R(r) { x0 += x1; x1 = TF_ROT(x1, r); x1 ^= x0; }
  TF_R(13) TF_R(15) TF_R(26) TF_R(6)   x0 += k1;  x1 += ks2 + 1u;
  TF_R(17) TF_R(29) TF_R(16) TF_R(24)  x0 += ks2; x1 += k0 + 2u;
  TF_R(13) TF_R(15) TF_R(26) TF_R(6)   x0 += k0;  x1 += k1 + 3u;
  TF_R(17) TF_R(29) TF_R(16) TF_R(24)  x0 += k1;  x1 += ks2 + 4u;
  TF_R(13) TF_R(15) TF_R(26) TF_R(6)   x0 += ks2; x1 += k0 + 5u;
#undef TF_R
#undef TF_ROT
  o0 = x0; o1 = x1;
}

// RNG MODE: jax_threefry_partitionable=True (default in JAX >= 0.4.36):
// random_bits(key,32)[n] = o0^o1 of tf(key,(0,n)); split(key,m)[i] = tf(key,(0,i)).
__device__ __forceinline__ unsigned tf_xor(unsigned k0, unsigned k1, unsigned c0, unsigned c1) {
  unsigned a, b; tf2x32(k0, k1, c0, c1, a, b); return a ^ b;
}

__device__ __forceinline__ float bits_to_unit(unsigned bits) {
  return __uint_as_float(0x3f800000u | (bits >> 9)) - 1.0f;
}

// ---------------- fast accurate double log (~1e-13 rel) ----------------
__device__ __forceinline__ double dlog(double x) {
  unsigned long long ub = (unsigned long long)__double_as_longlong(x);
  int e = (int)((ub >> 52) & 0x7FFull) - 1022;
  double m = __longlong_as_double((long long)((ub & 0x000FFFFFFFFFFFFFull) | 0x3FE0000000000000ull));
  if (m < 0.70710678118654752440) { m *= 2.0; e -= 1; }
  double r = (m - 1.0) / (m + 1.0);
  double z = r * r;
  double s = fma(z, fma(z, fma(z, fma(z, fma(z, fma(z, 1.0/15.0, 1.0/13.0),
                1.0/11.0), 1.0/9.0), 1.0/7.0), 1.0/5.0), 1.0/3.0);
  double t2 = 2.0 * r;
  return fma((double)e, 0.69314718055994530942, fma(t2 * z, s, t2));
}

// gumbel for flat index n under key (kk0,kk1), fp32-rounded at each log (matches XLA)
__device__ __forceinline__ float gumbel_of(unsigned kk0, unsigned kk1, unsigned n) {
  unsigned bits = tf_xor(kk0, kk1, 0u, n);
  float f = bits_to_unit(bits);
  float uu = (f == 0.0f) ? 1.17549435e-38f : f;
  float t1 = (float)dlog((double)uu);
  return -(float)dlog((double)(-t1));
}

__device__ __forceinline__ double blockReduce256(double v, double* lds) {
  #pragma unroll
  for (int off = 32; off > 0; off >>= 1) v += __shfl_down(v, off);
  __syncthreads();
  if ((threadIdx.x & 63) == 0) lds[threadIdx.x >> 6] = v;
  __syncthreads();
  return lds[0] + lds[1] + lds[2] + lds[3];
}

// ---------------- K0: all small RNG draws ----------------
__global__ void k_rng(unsigned* __restrict__ keys_out, int* __restrict__ radius,
                      float* __restrict__ u_acc) {
  int t = threadIdx.x;
  unsigned krad0, krad1, ksamp0, ksamp1, kacc0, kacc1;
  tf2x32(0u, 42u, 0u, 0u, krad0, krad1);
  tf2x32(0u, 42u, 0u, 1u, ksamp0, ksamp1);
  tf2x32(0u, 42u, 0u, 2u, kacc0, kacc1);
  if (t < MAXR) {
    unsigned a, c;
    tf2x32(ksamp0, ksamp1, 0u, (unsigned)t, a, c);
    keys_out[2*t] = a; keys_out[2*t+1] = c;
  }
  unsigned k10, k11, k20, k21;
  tf2x32(krad0, krad1, 0u, 0u, k10, k11);
  tf2x32(krad0, krad1, 0u, 1u, k20, k21);
  unsigned hi = tf_xor(k10, k11, 0u, (unsigned)t);
  unsigned lo = tf_xor(k20, k21, 0u, (unsigned)t);
  unsigned off = ((hi % 31u) * 4u + (lo % 31u)) % 31u;
  radius[t] = 1 + (int)off;
  unsigned ab = tf_xor(kacc0, kacc1, 0u, (unsigned)t);
  u_acc[t] = bits_to_unit(ab);
}

// ---------------- K1a: transpose x -> xT[D][B] ----------------
__global__ void k_transpose(const float* __restrict__ x, float* __restrict__ xT) {
  __shared__ float tile[32][33];
  int bx = blockIdx.x & 127;
  int by = blockIdx.x >> 7;
  int tx = threadIdx.x & 31, ty = threadIdx.x >> 5;
  #pragma unroll
  for (int r = 0; r < 32; r += 8)
    tile[ty + r][tx] = x[(size_t)(by*32 + ty + r)*DD + bx*32 + tx];
  __syncthreads();
  #pragma unroll
  for (int r = 0; r < 32; r += 8)
    xT[(size_t)(bx*32 + ty + r)*BB + by*32 + tx] = tile[tx][ty + r];
}

// ---------------- K1b: split-K fp32 GEMM ----------------
__global__ __launch_bounds__(256) void k_gemm(const float* __restrict__ xT, const float* __restrict__ W,
                                              float* __restrict__ Cpart, int klen) {
  __shared__ float As[32][132];
  __shared__ float Bs[32][132];
  int nt = blockIdx.x, mt = blockIdx.y, kc = blockIdx.z;
  int t = threadIdx.x;
  int tx = t & 15, ty = t >> 4;
  int k0 = kc * klen;
  float acc[8][8] = {};
  for (int kb = 0; kb < klen; kb += 32) {
    #pragma unroll
    for (int p = 0; p < 4; p++) {
      int f = t + 256*p;
      int kk = f >> 5, mq = f & 31;
      *(float4*)&As[kk][mq*4] = *(const float4*)&xT[(size_t)(k0+kb+kk)*BB + mt*128 + mq*4];
      *(float4*)&Bs[kk][mq*4] = *(const float4*)&W [(size_t)(k0+kb+kk)*DD + nt*128 + mq*4];
    }
    __syncthreads();
    for (int kk = 0; kk < 32; kk++) {
      float a[8], bv[8];
      *(float4*)&a[0]  = *(const float4*)&As[kk][ty*8];
      *(float4*)&a[4]  = *(const float4*)&As[kk][ty*8+4];
      *(float4*)&bv[0] = *(const float4*)&Bs[kk][tx*8];
      *(float4*)&bv[4] = *(const float4*)&Bs[kk][tx*8+4];
      #pragma unroll
      for (int i = 0; i < 8; i++)
        #pragma unroll
        for (int j = 0; j < 8; j++)
          acc[i][j] = fmaf(a[i], bv[j], acc[i][j]);
    }
    __syncthreads();
  }
  float* Cp = Cpart + (size_t)kc * BB * DD;
  #pragma unroll
  for (int i = 0; i < 8; i++) {
    int m = mt*128 + ty*8 + i;
    float* row = &Cp[(size_t)m*DD + nt*128 + tx*8];
    *(float4*)&row[0] = *(float4*)&acc[i][0];
    *(float4*)&row[4] = *(float4*)&acc[i][4];
  }
}

// ---------------- K1c: reduce split-K, add bias, make sc_x ----------------
__global__ void k_reduce(const float* __restrict__ Cpart, const float* __restrict__ bias,
                         const float* __restrict__ x, float* __restrict__ grad,
                         float* __restrict__ sc, int KS) {
  int i = blockIdx.x * 256 + threadIdx.x;
  float acc = 0.0f;
  for (int kc = 0; kc < KS; kc++) acc += Cpart[(size_t)kc * BB * DD + i];
  float g = acc + bias[i & (DD-1)];
  grad[i] = g;
  float xv = x[i];
  sc[i] = (1.0f - 2.0f*xv) * g * 0.5f;
}

// ---------------- K2: score_x ----------------
__global__ __launch_bounds__(256) void k_score(const float* __restrict__ x, const float* __restrict__ grad,
                                               const float* __restrict__ bias, double* __restrict__ score) {
  int b = blockIdx.x, t = threadIdx.x;
  double s1 = 0.0, s2 = 0.0;
  for (int k = 0; k < 16; k++) {
    int d = t + 256*k; size_t o = (size_t)b*DD + d;
    double xv = x[o];
    s1 += xv * (double)grad[o];
    s2 += xv * (double)bias[d];
  }
  __shared__ double lds[4];
  double S1 = blockReduce256(s1, lds);
  double S2 = blockReduce256(s2, lds);
  if (t == 0) score[b] = 0.5 * (S1 + S2);
}

// ---------------- K4: per (row,step) top-4 of sc_x + gumbel ----------------
__global__ __launch_bounds__(256) void k_cand(const float* __restrict__ sc_x,
                                              const unsigned* __restrict__ keys,
                                              int* __restrict__ cand_i) {
  int blk = blockIdx.x;
  int b = blk / MAXR, j = blk % MAXR;
  unsigned kk0 = keys[2*j], kk1 = keys[2*j+1];
  int t = threadIdx.x;
  float v[16];
  #pragma unroll
  for (int p = 0; p < 16; p++) {
    int d = t + 256*p;
    v[p] = sc_x[(size_t)b*DD + d] + gumbel_of(kk0, kk1, (unsigned)(b*DD + d));
  }
  unsigned alive = 0xFFFFu;
  // cached per-thread local best (value desc, index asc)
  float lv = -INFINITY; int li = 0x7FFFFFFF;
  #pragma unroll
  for (int p = 0; p < 16; p++) {
    if (v[p] > lv) { lv = v[p]; li = t + 256*p; }
  }
  __shared__ float ls_v[4];
  __shared__ int   ls_i[4];
  __shared__ int   win_s;
  for (int r = 0; r < NCAND; r++) {
    float bv = lv; int bi = li;
    #pragma unroll
    for (int off = 32; off > 0; off >>= 1) {
      float ov = __shfl_down(bv, off);
      int   oi = __shfl_down(bi, off);
      if (ov > bv || (ov == bv && oi < bi)) { bv = ov; bi = oi; }
    }
    if ((t & 63) == 0) { ls_v[t >> 6] = bv; ls_i[t >> 6] = bi; }
    __syncthreads();
    if (t == 0) {
      float fv = ls_v[0]; int fi = ls_i[0];
      #pragma unroll
      for (int w = 1; w < 4; w++)
        if (ls_v[w] > fv || (ls_v[w] == fv && ls_i[w] < fi)) { fv = ls_v[w]; fi = ls_i[w]; }
      win_s = fi;
      cand_i[(size_t)blk * NCAND + r] = fi;
    }
    __syncthreads();
    if (r < NCAND - 1) {
      int wi = win_s;
      if (t == (wi & 255)) {   // only the winner's thread rescans
        alive &= ~(1u << (wi >> 8));
        lv = -INFINITY; li = 0x7FFFFFFF;
        #pragma unroll
        for (int p = 0; p < 16; p++) {
          if (((alive >> p) & 1u) && v[p] > lv) { lv = v[p]; li = t + 256*p; }
        }
      }
    }
  }
}

// ---------------- K5: per-row blocked-chain resolution w/ exact fallback ----------------
__global__ __launch_bounds__(256) void k_select(const int* __restrict__ cand_i,
                                                const float* __restrict__ sc_x,
                                                const unsigned* __restrict__ keys,
                                                int* __restrict__ idx_all) {
  int b = blockIdx.x, t = threadIdx.x;
  __shared__ unsigned mask[128];
  __shared__ int pick_s;
  __shared__ float ls_v[4];
  __shared__ int   ls_i[4];
  if (t < 128) mask[t] = 0u;
  __syncthreads();
  for (int j = 0; j < MAXR; j++) {
    if (t == 0) {
      const int* ci = &cand_i[(size_t)(b*MAXR + j) * NCAND];
      int pick = -1;
      #pragma unroll
      for (int r = 0; r < NCAND; r++) {
        int idx = ci[r];
        if (pick < 0 && !((mask[idx >> 5] >> (idx & 31)) & 1u)) pick = idx;
      }
      pick_s = pick;
    }
    __syncthreads();
    if (pick_s < 0) {
      // rare: all 4 candidates blocked -> exact full masked argmax recompute
      unsigned kk0 = keys[2*j], kk1 = keys[2*j+1];
      float lv = -INFINITY; int li = 0x7FFFFFFF;
      for (int p = 0; p < 16; p++) {
        int d = t + 256*p;
        if ((mask[d >> 5] >> (d & 31)) & 1u) continue;
        float vv = sc_x[(size_t)b*DD + d] + gumbel_of(kk0, kk1, (unsigned)(b*DD + d));
        if (vv > lv || (vv == lv && d < li)) { lv = vv; li = d; }
      }
      float bv = lv; int bi = li;
      #pragma unroll
      for (int off = 32; off > 0; off >>= 1) {
        float ov = __shfl_down(bv, off);
        int   oi = __shfl_down(bi, off);
        if (ov > bv || (ov == bv && oi < bi)) { bv = ov; bi = oi; }
      }
      if ((t & 63) == 0) { ls_v[t >> 6] = bv; ls_i[t >> 6] = bi; }
      __syncthreads();
      if (t == 0) {
        float fv = ls_v[0]; int fi = ls_i[0];
        #pragma unroll
        for (int w = 1; w < 4; w++)
          if (ls_v[w] > fv || (ls_v[w] == fv && ls_i[w] < fi)) { fv = ls_v[w]; fi = ls_i[w]; }
        pick_s = fi;
      }
      __syncthreads();
    }
    if (t == 0) {
      int pk = pick_s;
      idx_all[b*MAXR + j] = pk;
      mask[pk >> 5] |= (1u << (pk & 31));
    }
    __syncthreads();
  }
}

// ---------------- K6: y, grad_y (incremental), sc_y, score_y ----------------
__global__ __launch_bounds__(256) void k_y(const float* __restrict__ x, const float* __restrict__ W,
    const float* __restrict__ bias, const float* __restrict__ grad_x,
    const int* __restrict__ idx_all, const int* __restrict__ radius,
    float* __restrict__ yv, float* __restrict__ sc_y, double* __restrict__ score_y) {
  int b = blockIdx.x, t = threadIdx.x;
  __shared__ int   fidx[MAXR];
  __shared__ float fsgn[MAXR];
  int nf = radius[b];
  if (t < nf) {
    int id = idx_all[b*MAXR + t];
    fidx[t] = id;
    fsgn[t] = 1.0f - 2.0f * x[(size_t)b*DD + id];
  }
  __syncthreads();
  double s1 = 0.0, s2 = 0.0;
  for (int k = 0; k < 16; k++) {
    int d = t + 256*k;
    size_t o = (size_t)b*DD + d;
    float g = grad_x[o];
    float xval = x[o];
    float yval = xval;
    for (int jj = 0; jj < nf; jj++) {
      g = fmaf(fsgn[jj], W[(size_t)fidx[jj]*DD + d], g);
      if (fidx[jj] == d) yval = 1.0f - xval;
    }
    yv[o] = yval;
    sc_y[o] = (1.0f - 2.0f*yval) * g * 0.5f;
    s1 += (double)yval * (double)g;
    s2 += (double)yval * (double)bias[d];
  }
  __shared__ double lds[4];
  double S1 = blockReduce256(s1, lds);
  double S2 = blockReduce256(s2, lds);
  if (t == 0) score_y[b] = 0.5 * (S1 + S2);
}

// ---------------- K7: masked log-softmax sums, accept, output ----------------
__global__ __launch_bounds__(256) void k_accept(const float* __restrict__ x, const float* __restrict__ yv,
    const float* __restrict__ sc_x, const float* __restrict__ sc_y,
    const int* __restrict__ idx_all, const int* __restrict__ radius,
    const double* __restrict__ score_x, const double* __restrict__ score_y,
    const float* __restrict__ u_acc, float* __restrict__ out) {
  int b = blockIdx.x, t = threadIdx.x;
  double sx = 0.0, sy = 0.0;
  for (int k = 0; k < 16; k++) {
    int d = t + 256*k; size_t o = (size_t)b*DD + d;
    sx += exp((double)sc_x[o]);
    sy += exp((double)sc_y[o]);
  }
  __shared__ double lds[4];
  double S = blockReduce256(sx, lds);
  double T = blockReduce256(sy, lds);
  __shared__ float accf;
  if (t == 0) {
    int nf = radius[b];
    const int* ia = &idx_all[b*MAXR];
    double lf = 0.0, pre = 0.0;
    for (int jj = 0; jj < MAXR; jj++) {
      int id = ia[jj];
      double scv = (double)sc_x[(size_t)b*DD + id];
      if (jj < nf) lf += scv - dlog(S - pre);
      pre += exp(scv);
    }
    double lb = 0.0, suf = 0.0;
    for (int jj = MAXR-1; jj >= 0; jj--) {
      int id = ia[jj];
      double scv = (double)sc_y[(size_t)b*DD + id];
      if (jj < nf) lb += scv - dlog(T - suf);
      suf += exp(scv);
    }
    double log_acc = (lb + score_y[b]) - (lf + score_x[b]);
    accf = (exp(log_acc) >= (double)u_acc[b]) ? 1.0f : 0.0f;
  }
  __syncthreads();
  float a = accf;
  for (int k = 0; k < 16; k++) {
    int d = t + 256*k; size_t o = (size_t)b*DD + d;
    out[o] = a * yv[o] + (1.0f - a) * x[o];
  }
}

extern "C" void kernel_launch(void* const* d_in, const int* in_sizes, int n_in,
                              void* d_out, int out_size, void* d_ws, size_t ws_size,
                              hipStream_t stream) {
  const float* x    = (const float*)d_in[0];
  const float* W    = (const float*)d_in[1];
  const float* bias = (const float*)d_in[2];
  float* out = (float*)d_out;
  char* ws = (char*)d_ws;
  const size_t MB = 1ull << 20;

  float*    grad_x  = (float*)   (ws + 0*MB);
  float*    sc_x    = (float*)   (ws + 4*MB);
  float*    sc_y    = (float*)   (ws + 8*MB);
  float*    yv      = (float*)   (ws + 12*MB);
  float*    xT      = (float*)   (ws + 16*MB);
  int*      cand_i  = (int*)     (ws + 20*MB);
  int*      idx_all = (int*)     (ws + 21*MB);
  int*      radius  = (int*)     (ws + 21*MB + 64*1024);
  float*    u_acc   = (float*)   (ws + 21*MB + 68*1024);
  unsigned* keys    = (unsigned*)(ws + 21*MB + 72*1024);
  double*   score_x = (double*)  (ws + 21*MB + 80*1024);
  double*   score_y = (double*)  (ws + 21*MB + 96*1024);
  float*    Cpart   = (float*)   (ws + 22*MB);

  size_t base = 22*MB;
  int KS = 1;
  if      (ws_size >= base + 32*MB) KS = 8;
  else if (ws_size >= base + 16*MB) KS = 4;
  else if (ws_size >= base +  8*MB) KS = 2;

  k_rng      <<<1, 256, 0, stream>>>(keys, radius, u_acc);
  k_transpose<<<1024, 256, 0, stream>>>(x, xT);
  k_gemm     <<<dim3(DD/128, BB/128, KS), 256, 0, stream>>>(xT, W, Cpart, DD/KS);
  k_reduce   <<<BB*DD/256, 256, 0, stream>>>(Cpart, bias, x, grad_x, sc_x, KS);
  k_score    <<<BB, 256, 0, stream>>>(x, grad_x, bias, score_x);
  k_cand     <<<BB*MAXR, 256, 0, stream>>>(sc_x, keys, cand_i);
  k_select   <<<BB, 256, 0, stream>>>(cand_i, sc_x, keys, idx_all);
  k_y        <<<BB, 256, 0, stream>>>(x, W, bias, grad_x, idx_all, radius, yv, sc_y, score_y);
  k_accept   <<<BB, 256, 0, stream>>>(x, yv, sc_x, sc_y, idx_all, radius, score_x, score_y, u_acc, out);
}

// Round 3
// 370.051 us; speedup vs baseline: 1.9396x; 1.1801x over previous
//
#include <hip/hip_runtime.h>
#include <math.h>

#define BB 256
#define DD 4096
#define MAXR 31
#define NCAND 4
#define CAP 512
// filter: u < U_THRESH  =>  g(u) < 3.8 (incl. fp32 rounding slop). GUARD=4.0 check.
#define U_THRESH 0.9778f
#define GUARD 4.0f

// ---------------- threefry2x32 (JAX schedule) ----------------
__device__ __forceinline__ void tf2x32(unsigned k0, unsigned k1, unsigned c0, unsigned c1,
                                       unsigned &o0, unsigned &o1) {
  unsigned ks2 = k0 ^ k1 ^ 0x1BD11BDAu;
  unsigned x0 = c0 + k0;
  unsigned x1 = c1 + k1;
#define TF_ROT(v, r) (((v) << (r)) | ((v) >> (32 - (r))))
#define TF_R(r) { x0 += x1; x1 = TF_ROT(x1, r); x1 ^= x0; }
  TF_R(13) TF_R(15) TF_R(26) TF_R(6)   x0 += k1;  x1 += ks2 + 1u;
  TF_R(17) TF_R(29) TF_R(16) TF_R(24)  x0 += ks2; x1 += k0 + 2u;
  TF_R(13) TF_R(15) TF_R(26) TF_R(6)   x0 += k0;  x1 += k1 + 3u;
  TF_R(17) TF_R(29) TF_R(16) TF_R(24)  x0 += k1;  x1 += ks2 + 4u;
  TF_R(13) TF_R(15) TF_R(26) TF_R(6)   x0 += ks2; x1 += k0 + 5u;
#undef TF_R
#undef TF_ROT
  o0 = x0; o1 = x1;
}

__device__ __forceinline__ unsigned tf_xor(unsigned k0, unsigned k1, unsigned c0, unsigned c1) {
  unsigned a, b; tf2x32(k0, k1, c0, c1, a, b); return a ^ b;
}

__device__ __forceinline__ float bits_to_unit(unsigned bits) {
  return __uint_as_float(0x3f800000u | (bits >> 9)) - 1.0f;
}

// ---------------- fast accurate double log (~1e-13 rel) ----------------
__device__ __forceinline__ double dlog(double x) {
  unsigned long long ub = (unsigned long long)__double_as_longlong(x);
  int e = (int)((ub >> 52) & 0x7FFull) - 1022;
  double m = __longlong_as_double((long long)((ub & 0x000FFFFFFFFFFFFFull) | 0x3FE0000000000000ull));
  if (m < 0.70710678118654752440) { m *= 2.0; e -= 1; }
  double r = (m - 1.0) / (m + 1.0);
  double z = r * r;
  double s = fma(z, fma(z, fma(z, fma(z, fma(z, fma(z, 1.0/15.0, 1.0/13.0),
                1.0/11.0), 1.0/9.0), 1.0/7.0), 1.0/5.0), 1.0/3.0);
  double t2 = 2.0 * r;
  return fma((double)e, 0.69314718055994530942, fma(t2 * z, s, t2));
}

// gumbel from uniform u (u>0), fp32-rounded at each log (matches XLA)
__device__ __forceinline__ float gumbel_from_u(float f) {
  float uu = (f == 0.0f) ? 1.17549435e-38f : f;
  float t1 = (float)dlog((double)uu);
  return -(float)dlog((double)(-t1));
}

__device__ __forceinline__ float gumbel_of(unsigned kk0, unsigned kk1, unsigned n) {
  return gumbel_from_u(bits_to_unit(tf_xor(kk0, kk1, 0u, n)));
}

__device__ __forceinline__ double blockReduce256(double v, double* lds) {
  #pragma unroll
  for (int off = 32; off > 0; off >>= 1) v += __shfl_down(v, off);
  __syncthreads();
  if ((threadIdx.x & 63) == 0) lds[threadIdx.x >> 6] = v;
  __syncthreads();
  return lds[0] + lds[1] + lds[2] + lds[3];
}

// ---------------- K0: all small RNG draws ----------------
__global__ void k_rng(unsigned* __restrict__ keys_out, int* __restrict__ radius,
                      float* __restrict__ u_acc) {
  int t = threadIdx.x;
  unsigned krad0, krad1, ksamp0, ksamp1, kacc0, kacc1;
  tf2x32(0u, 42u, 0u, 0u, krad0, krad1);
  tf2x32(0u, 42u, 0u, 1u, ksamp0, ksamp1);
  tf2x32(0u, 42u, 0u, 2u, kacc0, kacc1);
  if (t < MAXR) {
    unsigned a, c;
    tf2x32(ksamp0, ksamp1, 0u, (unsigned)t, a, c);
    keys_out[2*t] = a; keys_out[2*t+1] = c;
  }
  unsigned k10, k11, k20, k21;
  tf2x32(krad0, krad1, 0u, 0u, k10, k11);
  tf2x32(krad0, krad1, 0u, 1u, k20, k21);
  unsigned hi = tf_xor(k10, k11, 0u, (unsigned)t);
  unsigned lo = tf_xor(k20, k21, 0u, (unsigned)t);
  unsigned off = ((hi % 31u) * 4u + (lo % 31u)) % 31u;
  radius[t] = 1 + (int)off;
  unsigned ab = tf_xor(kacc0, kacc1, 0u, (unsigned)t);
  u_acc[t] = bits_to_unit(ab);
}

// ---------------- K1a: transpose x -> xT[D][B] ----------------
__global__ void k_transpose(const float* __restrict__ x, float* __restrict__ xT) {
  __shared__ float tile[32][33];
  int bx = blockIdx.x & 127;
  int by = blockIdx.x >> 7;
  int tx = threadIdx.x & 31, ty = threadIdx.x >> 5;
  #pragma unroll
  for (int r = 0; r < 32; r += 8)
    tile[ty + r][tx] = x[(size_t)(by*32 + ty + r)*DD + bx*32 + tx];
  __syncthreads();
  #pragma unroll
  for (int r = 0; r < 32; r += 8)
    xT[(size_t)(bx*32 + ty + r)*BB + by*32 + tx] = tile[tx][ty + r];
}

// ---------------- K1b: split-K fp32 GEMM ----------------
__global__ __launch_bounds__(256) void k_gemm(const float* __restrict__ xT, const float* __restrict__ W,
                                              float* __restrict__ Cpart, int klen) {
  __shared__ float As[32][132];
  __shared__ float Bs[32][132];
  int nt = blockIdx.x, mt = blockIdx.y, kc = blockIdx.z;
  int t = threadIdx.x;
  int tx = t & 15, ty = t >> 4;
  int k0 = kc * klen;
  float acc[8][8] = {};
  for (int kb = 0; kb < klen; kb += 32) {
    #pragma unroll
    for (int p = 0; p < 4; p++) {
      int f = t + 256*p;
      int kk = f >> 5, mq = f & 31;
      *(float4*)&As[kk][mq*4] = *(const float4*)&xT[(size_t)(k0+kb+kk)*BB + mt*128 + mq*4];
      *(float4*)&Bs[kk][mq*4] = *(const float4*)&W [(size_t)(k0+kb+kk)*DD + nt*128 + mq*4];
    }
    __syncthreads();
    for (int kk = 0; kk < 32; kk++) {
      float a[8], bv[8];
      *(float4*)&a[0]  = *(const float4*)&As[kk][ty*8];
      *(float4*)&a[4]  = *(const float4*)&As[kk][ty*8+4];
      *(float4*)&bv[0] = *(const float4*)&Bs[kk][tx*8];
      *(float4*)&bv[4] = *(const float4*)&Bs[kk][tx*8+4];
      #pragma unroll
      for (int i = 0; i < 8; i++)
        #pragma unroll
        for (int j = 0; j < 8; j++)
          acc[i][j] = fmaf(a[i], bv[j], acc[i][j]);
    }
    __syncthreads();
  }
  float* Cp = Cpart + (size_t)kc * BB * DD;
  #pragma unroll
  for (int i = 0; i < 8; i++) {
    int m = mt*128 + ty*8 + i;
    float* row = &Cp[(size_t)m*DD + nt*128 + tx*8];
    *(float4*)&row[0] = *(float4*)&acc[i][0];
    *(float4*)&row[4] = *(float4*)&acc[i][4];
  }
}

// ---------------- K1c: reduce split-K, add bias, make sc_x ----------------
__global__ void k_reduce(const float* __restrict__ Cpart, const float* __restrict__ bias,
                         const float* __restrict__ x, float* __restrict__ grad,
                         float* __restrict__ sc, int KS) {
  int i = blockIdx.x * 256 + threadIdx.x;
  float acc = 0.0f;
  for (int kc = 0; kc < KS; kc++) acc += Cpart[(size_t)kc * BB * DD + i];
  float g = acc + bias[i & (DD-1)];
  grad[i] = g;
  float xv = x[i];
  sc[i] = (1.0f - 2.0f*xv) * g * 0.5f;
}

// ---------------- K2: score_x + per-row max of sc_x ----------------
__global__ __launch_bounds__(256) void k_score(const float* __restrict__ x, const float* __restrict__ grad,
                                               const float* __restrict__ bias, double* __restrict__ score,
                                               float* __restrict__ scmax) {
  int b = blockIdx.x, t = threadIdx.x;
  double s1 = 0.0, s2 = 0.0;
  float mx = -INFINITY;
  for (int k = 0; k < 16; k++) {
    int d = t + 256*k; size_t o = (size_t)b*DD + d;
    float xvf = x[o];
    float gv = grad[o];
    float scv = (1.0f - 2.0f*xvf) * gv * 0.5f;  // identical rounding to k_reduce
    mx = fmaxf(mx, scv);
    double xv = xvf;
    s1 += xv * (double)gv;
    s2 += xv * (double)bias[d];
  }
  __shared__ double lds[4];
  double S1 = blockReduce256(s1, lds);
  double S2 = blockReduce256(s2, lds);
  // max reduce
  #pragma unroll
  for (int off = 32; off > 0; off >>= 1) mx = fmaxf(mx, __shfl_down(mx, off));
  __shared__ float lmx[4];
  __syncthreads();
  if ((t & 63) == 0) lmx[t >> 6] = mx;
  __syncthreads();
  if (t == 0) {
    score[b] = 0.5 * (S1 + S2);
    scmax[b] = fmaxf(fmaxf(lmx[0], lmx[1]), fmaxf(lmx[2], lmx[3]));
  }
}

// ---------------- K4: per (row,step) top-4 via u-filter + exact fallback ----------------
__global__ __launch_bounds__(256) void k_cand(const float* __restrict__ sc_x,
                                              const unsigned* __restrict__ keys,
                                              const float* __restrict__ scmax,
                                              int* __restrict__ cand_i) {
  int blk = blockIdx.x;
  int b = blk / MAXR, j = blk % MAXR;
  unsigned kk0 = keys[2*j], kk1 = keys[2*j+1];
  int t = threadIdx.x;
  unsigned base = (unsigned)(b * DD);

  __shared__ int cnt;
  __shared__ int   lidx[CAP];
  __shared__ float lu[CAP];
  __shared__ float win_v_s;
  __shared__ int   win_i_s;
  __shared__ float ls_v[4];
  __shared__ int   ls_i[4];
  if (t == 0) cnt = 0;
  __syncthreads();

  // phase 1: threefry + uniform + cheap filter (the 97.8% fast path)
  #pragma unroll
  for (int p = 0; p < 16; p++) {
    int d = t + 256*p;
    unsigned bits = tf_xor(kk0, kk1, 0u, base + (unsigned)d);
    float f = bits_to_unit(bits);
    if (f >= U_THRESH) {
      int pos = atomicAdd(&cnt, 1);
      if (pos < CAP) { lidx[pos] = d; lu[pos] = f; }
    }
  }
  __syncthreads();
  int n = cnt;
  bool need_fallback = (n > CAP) || (n < NCAND);

  if (!need_fallback) {
    // phase 2: exact gumbel + top-4 over <=512 candidates (2 per thread)
    float v[2]; int di[2]; unsigned alive = 0u;
    #pragma unroll
    for (int q = 0; q < 2; q++) {
      int idx = t + 256*q;
      if (idx < n) {
        int d = lidx[idx];
        v[q] = sc_x[(size_t)b*DD + d] + gumbel_from_u(lu[idx]);
        di[q] = d;
        alive |= (1u << q);
      } else { v[q] = -INFINITY; di[q] = 0x7FFFFFFF; }
    }
    float v4 = -INFINITY;
    for (int r = 0; r < NCAND; r++) {
      float bv = -INFINITY; int bi = 0x7FFFFFFF;
      #pragma unroll
      for (int q = 0; q < 2; q++)
        if (((alive >> q) & 1u) && (v[q] > bv || (v[q] == bv && di[q] < bi))) { bv = v[q]; bi = di[q]; }
      #pragma unroll
      for (int off = 32; off > 0; off >>= 1) {
        float ov = __shfl_down(bv, off);
        int   oi = __shfl_down(bi, off);
        if (ov > bv || (ov == bv && oi < bi)) { bv = ov; bi = oi; }
      }
      if ((t & 63) == 0) { ls_v[t >> 6] = bv; ls_i[t >> 6] = bi; }
      __syncthreads();
      if (t == 0) {
        float fv = ls_v[0]; int fi = ls_i[0];
        #pragma unroll
        for (int w = 1; w < 4; w++)
          if (ls_v[w] > fv || (ls_v[w] == fv && ls_i[w] < fi)) { fv = ls_v[w]; fi = ls_i[w]; }
        win_v_s = fv; win_i_s = fi;
        cand_i[(size_t)blk * NCAND + r] = fi;
      }
      __syncthreads();
      int wd = win_i_s;
      v4 = win_v_s;
      #pragma unroll
      for (int q = 0; q < 2; q++) if (di[q] == wd) alive &= ~(1u << q);
    }
    // guarantee: every skipped element has v < scmax + 3.8 < scmax + GUARD
    if (v4 >= scmax[b] + GUARD) return;
    need_fallback = true;
    __syncthreads();
  }

  // fallback: full exact computation (statistically ~never; preserves exactness)
  {
    float v[16];
    #pragma unroll
    for (int p = 0; p < 16; p++) {
      int d = t + 256*p;
      v[p] = sc_x[(size_t)b*DD + d] + gumbel_of(kk0, kk1, base + (unsigned)d);
    }
    unsigned alive = 0xFFFFu;
    float lv = -INFINITY; int li = 0x7FFFFFFF;
    #pragma unroll
    for (int p = 0; p < 16; p++)
      if (v[p] > lv) { lv = v[p]; li = t + 256*p; }
    for (int r = 0; r < NCAND; r++) {
      float bv = lv; int bi = li;
      #pragma unroll
      for (int off = 32; off > 0; off >>= 1) {
        float ov = __shfl_down(bv, off);
        int   oi = __shfl_down(bi, off);
        if (ov > bv || (ov == bv && oi < bi)) { bv = ov; bi = oi; }
      }
      if ((t & 63) == 0) { ls_v[t >> 6] = bv; ls_i[t >> 6] = bi; }
      __syncthreads();
      if (t == 0) {
        float fv = ls_v[0]; int fi = ls_i[0];
        #pragma unroll
        for (int w = 1; w < 4; w++)
          if (ls_v[w] > fv || (ls_v[w] == fv && ls_i[w] < fi)) { fv = ls_v[w]; fi = ls_i[w]; }
        win_i_s = fi;
        cand_i[(size_t)blk * NCAND + r] = fi;
      }
      __syncthreads();
      if (r < NCAND - 1) {
        int wi = win_i_s;
        if (t == (wi & 255)) {
          alive &= ~(1u << (wi >> 8));
          lv = -INFINITY; li = 0x7FFFFFFF;
          #pragma unroll
          for (int p = 0; p < 16; p++)
            if (((alive >> p) & 1u) && v[p] > lv) { lv = v[p]; li = t + 256*p; }
        }
      }
    }
  }
}

// ---------------- K5: per-row blocked-chain resolution w/ exact fallback ----------------
__global__ __launch_bounds__(256) void k_select(const int* __restrict__ cand_i,
                                                const float* __restrict__ sc_x,
                                                const unsigned* __restrict__ keys,
                                                int* __restrict__ idx_all) {
  int b = blockIdx.x, t = threadIdx.x;
  __shared__ unsigned mask[128];
  __shared__ int pick_s;
  __shared__ float ls_v[4];
  __shared__ int   ls_i[4];
  if (t < 128) mask[t] = 0u;
  __syncthreads();
  for (int j = 0; j < MAXR; j++) {
    if (t == 0) {
      const int* ci = &cand_i[(size_t)(b*MAXR + j) * NCAND];
      int pick = -1;
      #pragma unroll
      for (int r = 0; r < NCAND; r++) {
        int idx = ci[r];
        if (pick < 0 && !((mask[idx >> 5] >> (idx & 31)) & 1u)) pick = idx;
      }
      pick_s = pick;
    }
    __syncthreads();
    if (pick_s < 0) {
      unsigned kk0 = keys[2*j], kk1 = keys[2*j+1];
      float lv = -INFINITY; int li = 0x7FFFFFFF;
      for (int p = 0; p < 16; p++) {
        int d = t + 256*p;
        if ((mask[d >> 5] >> (d & 31)) & 1u) continue;
        float vv = sc_x[(size_t)b*DD + d] + gumbel_of(kk0, kk1, (unsigned)(b*DD + d));
        if (vv > lv || (vv == lv && d < li)) { lv = vv; li = d; }
      }
      float bv = lv; int bi = li;
      #pragma unroll
      for (int off = 32; off > 0; off >>= 1) {
        float ov = __shfl_down(bv, off);
        int   oi = __shfl_down(bi, off);
        if (ov > bv || (ov == bv && oi < bi)) { bv = ov; bi = oi; }
      }
      if ((t & 63) == 0) { ls_v[t >> 6] = bv; ls_i[t >> 6] = bi; }
      __syncthreads();
      if (t == 0) {
        float fv = ls_v[0]; int fi = ls_i[0];
        #pragma unroll
        for (int w = 1; w < 4; w++)
          if (ls_v[w] > fv || (ls_v[w] == fv && ls_i[w] < fi)) { fv = ls_v[w]; fi = ls_i[w]; }
        pick_s = fi;
      }
      __syncthreads();
    }
    if (t == 0) {
      int pk = pick_s;
      idx_all[b*MAXR + j] = pk;
      mask[pk >> 5] |= (1u << (pk & 31));
    }
    __syncthreads();
  }
}

// ---------------- K6: y, grad_y (incremental), sc_y, score_y ----------------
__global__ __launch_bounds__(256) void k_y(const float* __restrict__ x, const float* __restrict__ W,
    const float* __restrict__ bias, const float* __restrict__ grad_x,
    const int* __restrict__ idx_all, const int* __restrict__ radius,
    float* __restrict__ yv, float* __restrict__ sc_y, double* __restrict__ score_y) {
  int b = blockIdx.x, t = threadIdx.x;
  __shared__ int   fidx[MAXR];
  __shared__ float fsgn[MAXR];
  int nf = radius[b];
  if (t < nf) {
    int id = idx_all[b*MAXR + t];
    fidx[t] = id;
    fsgn[t] = 1.0f - 2.0f * x[(size_t)b*DD + id];
  }
  __syncthreads();
  double s1 = 0.0, s2 = 0.0;
  for (int k = 0; k < 16; k++) {
    int d = t + 256*k;
    size_t o = (size_t)b*DD + d;
    float g = grad_x[o];
    float xval = x[o];
    float yval = xval;
    for (int jj = 0; jj < nf; jj++) {
      g = fmaf(fsgn[jj], W[(size_t)fidx[jj]*DD + d], g);
      if (fidx[jj] == d) yval = 1.0f - xval;
    }
    yv[o] = yval;
    sc_y[o] = (1.0f - 2.0f*yval) * g * 0.5f;
    s1 += (double)yval * (double)g;
    s2 += (double)yval * (double)bias[d];
  }
  __shared__ double lds[4];
  double S1 = blockReduce256(s1, lds);
  double S2 = blockReduce256(s2, lds);
  if (t == 0) score_y[b] = 0.5 * (S1 + S2);
}

// ---------------- K7: masked log-softmax sums, accept, output ----------------
__global__ __launch_bounds__(256) void k_accept(const float* __restrict__ x, const float* __restrict__ yv,
    const float* __restrict__ sc_x, const float* __restrict__ sc_y,
    const int* __restrict__ idx_all, const int* __restrict__ radius,
    const double* __restrict__ score_x, const double* __restrict__ score_y,
    const float* __restrict__ u_acc, float* __restrict__ out) {
  int b = blockIdx.x, t = threadIdx.x;
  double sx = 0.0, sy = 0.0;
  for (int k = 0; k < 16; k++) {
    int d = t + 256*k; size_t o = (size_t)b*DD + d;
    sx += exp((double)sc_x[o]);
    sy += exp((double)sc_y[o]);
  }
  __shared__ double lds[4];
  double S = blockReduce256(sx, lds);
  double T = blockReduce256(sy, lds);
  __shared__ float accf;
  if (t == 0) {
    int nf = radius[b];
    const int* ia = &idx_all[b*MAXR];
    double lf = 0.0, pre = 0.0;
    for (int jj = 0; jj < MAXR; jj++) {
      int id = ia[jj];
      double scv = (double)sc_x[(size_t)b*DD + id];
      if (jj < nf) lf += scv - dlog(S - pre);
      pre += exp(scv);
    }
    double lb = 0.0, suf = 0.0;
    for (int jj = MAXR-1; jj >= 0; jj--) {
      int id = ia[jj];
      double scv = (double)sc_y[(size_t)b*DD + id];
      if (jj < nf) lb += scv - dlog(T - suf);
      suf += exp(scv);
    }
    double log_acc = (lb + score_y[b]) - (lf + score_x[b]);
    accf = (exp(log_acc) >= (double)u_acc[b]) ? 1.0f : 0.0f;
  }
  __syncthreads();
  float a = accf;
  for (int k = 0; k < 16; k++) {
    int d = t + 256*k; size_t o = (size_t)b*DD + d;
    out[o] = a * yv[o] + (1.0f - a) * x[o];
  }
}

extern "C" void kernel_launch(void* const* d_in, const int* in_sizes, int n_in,
                              void* d_out, int out_size, void* d_ws, size_t ws_size,
                              hipStream_t stream) {
  const float* x    = (const float*)d_in[0];
  const float* W    = (const float*)d_in[1];
  const float* bias = (const float*)d_in[2];
  float* out = (float*)d_out;
  char* ws = (char*)d_ws;
  const size_t MB = 1ull << 20;

  float*    grad_x  = (float*)   (ws + 0*MB);
  float*    sc_x    = (float*)   (ws + 4*MB);
  float*    sc_y    = (float*)   (ws + 8*MB);
  float*    yv      = (float*)   (ws + 12*MB);
  float*    xT      = (float*)   (ws + 16*MB);
  int*      cand_i  = (int*)     (ws + 20*MB);
  int*      idx_all = (int*)     (ws + 21*MB);
  int*      radius  = (int*)     (ws + 21*MB + 64*1024);
  float*    u_acc   = (float*)   (ws + 21*MB + 68*1024);
  unsigned* keys    = (unsigned*)(ws + 21*MB + 72*1024);
  double*   score_x = (double*)  (ws + 21*MB + 80*1024);
  double*   score_y = (double*)  (ws + 21*MB + 96*1024);
  float*    scmax   = (float*)   (ws + 21*MB + 112*1024);
  float*    Cpart   = (float*)   (ws + 22*MB);

  size_t base = 22*MB;
  int KS = 1;
  if      (ws_size >= base + 32*MB) KS = 8;
  else if (ws_size >= base + 16*MB) KS = 4;
  else if (ws_size >= base +  8*MB) KS = 2;

  k_rng      <<<1, 256, 0, stream>>>(keys, radius, u_acc);
  k_transpose<<<1024, 256, 0, stream>>>(x, xT);
  k_gemm     <<<dim3(DD/128, BB/128, KS), 256, 0, stream>>>(xT, W, Cpart, DD/KS);
  k_reduce   <<<BB*DD/256, 256, 0, stream>>>(Cpart, bias, x, grad_x, sc_x, KS);
  k_score    <<<BB, 256, 0, stream>>>(x, grad_x, bias, score_x, scmax);
  k_cand     <<<BB*MAXR, 256, 0, stream>>>(sc_x, keys, scmax, cand_i);
  k_select   <<<BB, 256, 0, stream>>>(cand_i, sc_x, keys, idx_all);
  k_y        <<<BB, 256, 0, stream>>>(x, W, bias, grad_x, idx_all, radius, yv, sc_y, score_y);
  k_accept   <<<BB, 256, 0, stream>>>(x, yv, sc_x, sc_y, idx_all, radius, score_x, score_y, u_acc, out);
}